// Round 2
// baseline (487.162 us; speedup 1.0000x reference)
//
#include <hip/hip_runtime.h>
#include <stdint.h>

// ---------------------------------------------------------------------------
// Problem constants: E=64 H=64 PRE1=512 BNK=1024 S=256 P=16 B=4096
// Attention branch is dead code (softmax over size-1 axis == 1.0).
// v2: M=128 rows/WG (512 threads, 8 waves), X tile aliased inside Y1 tile,
//     LDS = 128 KiB, explicit 2-deep B prefetch, nontemporal output stores.
// ---------------------------------------------------------------------------

typedef __bf16 bf16x8 __attribute__((ext_vector_type(8)));
typedef float  f32x4  __attribute__((ext_vector_type(4)));

// workspace layout (bytes)
#define BP1_OFF 0               // Wp1 packed bf16: 32 nt * 4 kb * 64 * 16 B = 131072
#define BP2_OFF 131072          // Wp2 packed bf16: 64 nt * 16 kb * 64 * 16 B = 1048576
#define A1_OFF  1179648         // 512 f32
#define C1_OFF  1181696         // 512 f32
#define A2_OFF  1183744         // 1024 f32
#define C2_OFF  1187840         // 1024 f32
#define SW_OFF  1191936         // 192 f32: SW0[64] SW1[64] SB[64] (0.05 folded)

__device__ __forceinline__ unsigned short f2bf(float f) {
    union { float f; unsigned int u; } c; c.f = f;
    unsigned int u = c.u;
    return (unsigned short)((u + 0x7fffu + ((u >> 16) & 1u)) >> 16);
}

// ---------------------------------------------------------------------------
// Prep: pack weights into MFMA B-fragment order; fold bias+BN; fold 0.05.
// B-frag (16x16x32): lane l holds B[k = kb*32 + (l>>4)*8 + j][n = nt*16 + (l&15)]
// packed at ((nt*KB + kb)*64 + l)*16 bytes -> one coalesced 16 B/lane load.
// ---------------------------------------------------------------------------
__global__ void prep_kernel(
    const float* __restrict__ Wsp,  const float* __restrict__ bsp,
    const float* __restrict__ Wp1,  const float* __restrict__ bp1,
    const float* __restrict__ gp1,  const float* __restrict__ btp1,
    const float* __restrict__ mp1,  const float* __restrict__ vp1,
    const float* __restrict__ Wp2,  const float* __restrict__ bp2,
    const float* __restrict__ gp2,  const float* __restrict__ btp2,
    const float* __restrict__ mp2,  const float* __restrict__ vp2,
    unsigned char* __restrict__ ws)
{
    int t = blockIdx.x * 256 + threadIdx.x;

    if (t < 65536) {
        // Bpack2: N=1024 (64 ntiles), K=512 (16 kblocks)
        int nt = t >> 10, kb = (t >> 6) & 15, l = t & 63;
        int n  = nt * 16 + (l & 15);
        int k0 = kb * 32 + (l >> 4) * 8;
        unsigned int w0, w1, w2, w3;
        w0 = f2bf(Wp2[(k0+0)*1024+n]) | ((unsigned)f2bf(Wp2[(k0+1)*1024+n]) << 16);
        w1 = f2bf(Wp2[(k0+2)*1024+n]) | ((unsigned)f2bf(Wp2[(k0+3)*1024+n]) << 16);
        w2 = f2bf(Wp2[(k0+4)*1024+n]) | ((unsigned)f2bf(Wp2[(k0+5)*1024+n]) << 16);
        w3 = f2bf(Wp2[(k0+6)*1024+n]) | ((unsigned)f2bf(Wp2[(k0+7)*1024+n]) << 16);
        uint4 v; v.x = w0; v.y = w1; v.z = w2; v.w = w3;
        ((uint4*)(ws + BP2_OFF))[t] = v;
    } else if (t < 65536 + 8192) {
        // Bpack1: N=512 (32 ntiles), K=128 (4 kblocks)
        int q = t - 65536;
        int nt = q >> 8, kb = (q >> 6) & 3, l = q & 63;
        int n  = nt * 16 + (l & 15);
        int k0 = kb * 32 + (l >> 4) * 8;
        unsigned int w0, w1, w2, w3;
        w0 = f2bf(Wp1[(k0+0)*512+n]) | ((unsigned)f2bf(Wp1[(k0+1)*512+n]) << 16);
        w1 = f2bf(Wp1[(k0+2)*512+n]) | ((unsigned)f2bf(Wp1[(k0+3)*512+n]) << 16);
        w2 = f2bf(Wp1[(k0+4)*512+n]) | ((unsigned)f2bf(Wp1[(k0+5)*512+n]) << 16);
        w3 = f2bf(Wp1[(k0+6)*512+n]) | ((unsigned)f2bf(Wp1[(k0+7)*512+n]) << 16);
        uint4 v; v.x = w0; v.y = w1; v.z = w2; v.w = w3;
        ((uint4*)(ws + BP1_OFF))[q] = v;
    } else if (t < 65536 + 8192 + 1024) {
        int n = t - 73728;
        float a = gp2[n] * rsqrtf(vp2[n] + 1e-5f);
        ((float*)(ws + A2_OFF))[n] = a;
        ((float*)(ws + C2_OFF))[n] = btp2[n] + (bp2[n] - mp2[n]) * a;
    } else if (t < 65536 + 8192 + 1024 + 512) {
        int n = t - 74752;
        float a = gp1[n] * rsqrtf(vp1[n] + 1e-5f);
        ((float*)(ws + A1_OFF))[n] = a;
        ((float*)(ws + C1_OFF))[n] = btp1[n] + (bp1[n] - mp1[n]) * a;
    } else if (t < 65536 + 8192 + 1024 + 512 + 64) {
        int c = t - 75264;
        float* SWb = (float*)(ws + SW_OFF);
        SWb[c]       = 0.05f * Wsp[c];
        SWb[64 + c]  = 0.05f * Wsp[64 + c];
        SWb[128 + c] = 0.05f * bsp[c];
    }
}

// ---------------------------------------------------------------------------
// Fused kernel v2: one WG per (scene, i-half). M = 128 rows (r = il*16 + j,
// il 0..7, i = ih*8 + il). 512 threads = 8 waves.
// LDS (128 KiB, aliased):
//   phase A: Xs  bf16 [128][128], row stride 256 B, XOR swizzle ((r&7)<<4)
//            posf[32] parked at smem+32768 (outside Xs, inside future Y1s)
//   phase B: Y1s bf16 [128][512], row stride 1024 B, same swizzle (covers all)
// Barrier between mm1-compute (reads Xs) and Y1 writes makes aliasing safe.
// mm1: wave w -> Y1 cols [w*64, w*64+64)   (4 ntiles), acc[8][4]
// mm2: wave w -> Y2 cols [w*128, w*128+128) in 2 groups of 4 ntiles, acc[8][4]
// ---------------------------------------------------------------------------
__global__ __launch_bounds__(512, 2) void fused_kernel(
    const float* __restrict__ hst,   // (1,B,H) fp32
    const float* __restrict__ epos,  // (B,2) fp32
    const unsigned char* __restrict__ ws,
    float* __restrict__ out)         // (4096,1024) fp32
{
    __shared__ unsigned char smem[131072];
    float* posf = (float*)(smem + 32768);   // dead before any Y1s write

    const float* A1  = (const float*)(ws + A1_OFF);
    const float* C1  = (const float*)(ws + C1_OFF);
    const float* A2  = (const float*)(ws + A2_OFF);
    const float* C2  = (const float*)(ws + C2_OFF);
    const float* SWb = (const float*)(ws + SW_OFF);

    const int s    = blockIdx.x >> 1;
    const int ih   = blockIdx.x & 1;
    const int tid  = threadIdx.x;
    const int w    = tid >> 6;
    const int l    = tid & 63;
    const int quad = l >> 4;
    const int lrow = l & 15;

    if (tid < 32) posf[tid] = epos[s * 32 + tid];
    __syncthreads();

    // ---- Stage X into LDS (bf16, swizzled); 0.05 folded into SWb and h ----
    #pragma unroll
    for (int it = 0; it < 16; ++it) {
        int e = tid + it * 512;
        int r = e >> 6, p = e & 63;           // col pair c = 2p
        int j = r & 15, il = r >> 4;
        int i = ih * 8 + il;
        float v0, v1;
        if (p < 32) {
            int c0 = p * 2;
            float rx = posf[2 * j]     - posf[2 * i];
            float ry = posf[2 * j + 1] - posf[2 * i + 1];
            v0 = fmaf(rx, SWb[c0],     fmaf(ry, SWb[64 + c0],     SWb[128 + c0]));
            v1 = fmaf(rx, SWb[c0 + 1], fmaf(ry, SWb[64 + c0 + 1], SWb[128 + c0 + 1]));
        } else {
            const float* hp = hst + (s * 16 + j) * 64 + (p * 2 - 64);
            v0 = 0.05f * hp[0];
            v1 = 0.05f * hp[1];
        }
        unsigned int pk = (unsigned)f2bf(v0) | ((unsigned)f2bf(v1) << 16);
        int off = (p * 4) ^ ((r & 7) << 4);
        *(unsigned int*)(smem + r * 256 + off) = pk;
    }
    __syncthreads();

    const f32x4 fzero = {0.f, 0.f, 0.f, 0.f};

    // ---- mm1: acc[8][4] over cols [w*64, w*64+64), K=128 ----
    f32x4 acc1[8][4];
    #pragma unroll
    for (int rt = 0; rt < 8; ++rt)
        #pragma unroll
        for (int ct = 0; ct < 4; ++ct) acc1[rt][ct] = fzero;

    #pragma unroll
    for (int ks = 0; ks < 4; ++ks) {
        bf16x8 af[8];
        #pragma unroll
        for (int rt = 0; rt < 8; ++rt) {
            int row = rt * 16 + lrow;
            int off = (ks * 64 + quad * 16) ^ ((lrow & 7) << 4);
            af[rt] = *(const bf16x8*)(smem + row * 256 + off);
        }
        bf16x8 bfr[4];
        #pragma unroll
        for (int ct = 0; ct < 4; ++ct) {
            int nt = (w << 2) + ct;
            bfr[ct] = *(const bf16x8*)(ws + BP1_OFF + (((nt * 4 + ks) * 64 + l) << 4));
        }
        #pragma unroll
        for (int rt = 0; rt < 8; ++rt)
            #pragma unroll
            for (int ct = 0; ct < 4; ++ct)
                acc1[rt][ct] = __builtin_amdgcn_mfma_f32_16x16x32_bf16(af[rt], bfr[ct], acc1[rt][ct], 0, 0, 0);
    }
    __syncthreads();   // all waves done READING Xs; Y1s may now overwrite it

    // ---- mm1 epilogue: bn+relu -> bf16 -> Y1s (swizzled) ----
    #pragma unroll
    for (int ct = 0; ct < 4; ++ct) {
        int col = ((w << 2) + ct) * 16 + lrow;
        float a1 = A1[col], c1 = C1[col];
        #pragma unroll
        for (int rt = 0; rt < 8; ++rt) {
            #pragma unroll
            for (int reg = 0; reg < 4; ++reg) {
                int row = rt * 16 + quad * 4 + reg;
                float y = fmaxf(fmaf(acc1[rt][ct][reg], a1, c1), 0.f);
                int off = (col * 2) ^ ((row & 7) << 4);
                *(unsigned short*)(smem + row * 1024 + off) = f2bf(y);
            }
        }
    }
    __syncthreads();

    // ---- mm2: Y2 = relu(bn(Y1 @ Wp2)), maxpool over j, K=512 ----
    const unsigned char* bbase = ws + BP2_OFF;
    #pragma unroll 1
    for (int g = 0; g < 2; ++g) {
        f32x4 acc[8][4];
        #pragma unroll
        for (int rt = 0; rt < 8; ++rt)
            #pragma unroll
            for (int ct = 0; ct < 4; ++ct) acc[rt][ct] = fzero;

        // 2-deep B prefetch pipeline
        bf16x8 bfr[2][4];
        #pragma unroll
        for (int ct = 0; ct < 4; ++ct) {
            int nt = (w << 3) + (g << 2) + ct;
            bfr[0][ct] = *(const bf16x8*)(bbase + (((nt * 16 + 0) * 64 + l) << 4));
            bfr[1][ct] = *(const bf16x8*)(bbase + (((nt * 16 + 1) * 64 + l) << 4));
        }

        #pragma unroll
        for (int ks = 0; ks < 16; ++ks) {
            bf16x8 af[8];
            #pragma unroll
            for (int rt = 0; rt < 8; ++rt) {
                int row = rt * 16 + lrow;
                int off = (ks * 64 + quad * 16) ^ ((lrow & 7) << 4);
                af[rt] = *(const bf16x8*)(smem + row * 1024 + off);
            }
            bf16x8 nb[4];
            if (ks < 14) {
                #pragma unroll
                for (int ct = 0; ct < 4; ++ct) {
                    int nt = (w << 3) + (g << 2) + ct;
                    nb[ct] = *(const bf16x8*)(bbase + (((nt * 16 + ks + 2) * 64 + l) << 4));
                }
            }
            #pragma unroll
            for (int rt = 0; rt < 8; ++rt)
                #pragma unroll
                for (int ct = 0; ct < 4; ++ct)
                    acc[rt][ct] = __builtin_amdgcn_mfma_f32_16x16x32_bf16(af[rt], bfr[ks & 1][ct], acc[rt][ct], 0, 0, 0);
            if (ks < 14) {
                #pragma unroll
                for (int ct = 0; ct < 4; ++ct) bfr[ks & 1][ct] = nb[ct];
            }
        }

        // epilogue: bn+relu, max over j (4 regs + cross-quad shfl), store fp32
        #pragma unroll
        for (int ct = 0; ct < 4; ++ct) {
            int nt  = (w << 3) + (g << 2) + ct;
            int col = nt * 16 + lrow;
            float a2 = A2[col], c2 = C2[col];
            #pragma unroll
            for (int rt = 0; rt < 8; ++rt) {   // rt == i_local; j = quad*4 + reg
                float v0 = fmaxf(fmaf(acc[rt][ct][0], a2, c2), 0.f);
                float v1 = fmaxf(fmaf(acc[rt][ct][1], a2, c2), 0.f);
                float v2 = fmaxf(fmaf(acc[rt][ct][2], a2, c2), 0.f);
                float v3 = fmaxf(fmaf(acc[rt][ct][3], a2, c2), 0.f);
                float v = fmaxf(fmaxf(v0, v1), fmaxf(v2, v3));
                v = fmaxf(v, __shfl_xor(v, 16, 64));
                v = fmaxf(v, __shfl_xor(v, 32, 64));
                if (l < 16) {
                    int orow = s * 16 + ih * 8 + rt;
                    __builtin_nontemporal_store(v, &out[orow * 1024 + col]);
                }
            }
        }
    }
}

extern "C" void kernel_launch(void* const* d_in, const int* in_sizes, int n_in,
                              void* d_out, int out_size, void* d_ws, size_t ws_size,
                              hipStream_t stream) {
    const float* hst  = (const float*)d_in[0];
    const float* epos = (const float*)d_in[1];
    const float* Wsp  = (const float*)d_in[4];
    const float* bsp  = (const float*)d_in[5];
    const float* Wp1  = (const float*)d_in[20];
    const float* bp1  = (const float*)d_in[21];
    const float* gp1  = (const float*)d_in[22];
    const float* btp1 = (const float*)d_in[23];
    const float* mp1  = (const float*)d_in[24];
    const float* vp1  = (const float*)d_in[25];
    const float* Wp2  = (const float*)d_in[26];
    const float* bp2  = (const float*)d_in[27];
    const float* gp2  = (const float*)d_in[28];
    const float* btp2 = (const float*)d_in[29];
    const float* mp2  = (const float*)d_in[30];
    const float* vp2  = (const float*)d_in[31];
    unsigned char* ws = (unsigned char*)d_ws;
    float* out = (float*)d_out;

    prep_kernel<<<295, 256, 0, stream>>>(Wsp, bsp, Wp1, bp1, gp1, btp1, mp1, vp1,
                                         Wp2, bp2, gp2, btp2, mp2, vp2, ws);
    // 256 scenes * 2 i-halves, 512 threads (8 waves), M=128 rows per WG
    fused_kernel<<<512, 512, 0, stream>>>(hst, epos, ws, out);
}

// Round 4
// 292.071 us; speedup vs baseline: 1.6680x; 1.6680x over previous
//
#include <hip/hip_runtime.h>
#include <hip/hip_bf16.h>
#include <stdint.h>

// ---------------------------------------------------------------------------
// E=64 H=64 PRE1=512 BNK=1024 S=256 P=16 B=4096. Attention branch dead.
// v3b: algebraic decomposition. Z1[s,i,j,k] = rx*MX[k] + ry*MY[k] + HH[16s+j][k]
//     (rel is rank-2!). mm1 vanishes; mm2 A-frags built on the fly from LDS.
//     WG = (scene-pair, N-quarter): M=512 rows per B-pass; waves_per_eu(2,2)
//     unlocks the 256-VGPR budget (v1/v2 silently spilled at a 128 cap).
//     v3b fixes the bf16x2 pack (cvt_pk_bf16_f32 / manual RNE, no bit_cast
//     of __hip_bfloat162).
// ---------------------------------------------------------------------------

typedef __bf16 bf16x8 __attribute__((ext_vector_type(8)));
typedef __bf16 bf16x2 __attribute__((ext_vector_type(2)));
typedef float  f32x4  __attribute__((ext_vector_type(4)));

// workspace layout (bytes), all 16B-aligned
#define BP2_OFF 0                         // packed Wp2 bf16: 64nt*16kb*64l*16B = 1 MB
#define HH_OFF  (1u<<20)                  // HH bf16 [4096][512] = 4 MB
#define MX_OFF  (HH_OFF + (4u<<20))       // 512 f32
#define MY_OFF  (MX_OFF + 2048)           // 512 f32
#define CB_OFF  (MY_OFF + 2048)           // 512 f32
#define SH_OFF  (CB_OFF + 2048)           // 512 f32 (0.05*a1)
#define A2_OFF  (SH_OFF + 2048)           // 1024 f32
#define C2_OFF  (A2_OFF + 4096)           // 1024 f32
// total ~5.26 MB

__device__ __forceinline__ unsigned short f2bf(float f) {
    union { float f; unsigned u; } c; c.f = f;
    unsigned u = c.u;
    return (unsigned short)((u + 0x7fffu + ((u >> 16) & 1u)) >> 16);
}
__device__ __forceinline__ float bfbits2f(unsigned hi) {   // hi = bf16 in high 16
    union { unsigned u; float f; } c; c.u = hi; return c.f;
}
__device__ __forceinline__ unsigned pk_bf16(float a, float b) {
#if __has_builtin(__builtin_amdgcn_cvt_pk_bf16_f32)
    bf16x2 p = __builtin_amdgcn_cvt_pk_bf16_f32(a, b);
    union { bf16x2 v; unsigned u; } c; c.v = p; return c.u;
#else
    return (unsigned)f2bf(a) | ((unsigned)f2bf(b) << 16);
#endif
}

// ---------------------------------------------------------------------------
// prep1: pack Wp2 into MFMA B-frag order + fold all BN/bias/0.05 constants.
// B-frag (16x16x32): lane l holds B[k=kb*32+(l>>4)*8+j][n=nt*16+(l&15)],
// packed at ((nt*16+kb)*64+l)*16 bytes.
// ---------------------------------------------------------------------------
__global__ void prep1_kernel(
    const float* __restrict__ Wsp,  const float* __restrict__ bsp,
    const float* __restrict__ Wp1,  const float* __restrict__ bp1,
    const float* __restrict__ gp1,  const float* __restrict__ btp1,
    const float* __restrict__ mp1,  const float* __restrict__ vp1,
    const float* __restrict__ Wp2,  const float* __restrict__ bp2,
    const float* __restrict__ gp2,  const float* __restrict__ btp2,
    const float* __restrict__ mp2,  const float* __restrict__ vp2,
    unsigned char* __restrict__ ws)
{
    int t = blockIdx.x * 256 + threadIdx.x;
    if (t < 65536) {
        int nt = t >> 10, kb = (t >> 6) & 15, l = t & 63;
        int n  = nt * 16 + (l & 15);
        int k0 = kb * 32 + (l >> 4) * 8;
        unsigned w0, w1, w2, w3;
        w0 = f2bf(Wp2[(k0+0)*1024+n]) | ((unsigned)f2bf(Wp2[(k0+1)*1024+n]) << 16);
        w1 = f2bf(Wp2[(k0+2)*1024+n]) | ((unsigned)f2bf(Wp2[(k0+3)*1024+n]) << 16);
        w2 = f2bf(Wp2[(k0+4)*1024+n]) | ((unsigned)f2bf(Wp2[(k0+5)*1024+n]) << 16);
        w3 = f2bf(Wp2[(k0+6)*1024+n]) | ((unsigned)f2bf(Wp2[(k0+7)*1024+n]) << 16);
        uint4 v; v.x = w0; v.y = w1; v.z = w2; v.w = w3;
        ((uint4*)(ws + BP2_OFF))[t] = v;
    } else if (t < 65536 + 512) {
        int k = t - 65536;
        float a1 = gp1[k] * rsqrtf(vp1[k] + 1e-5f);
        float mx = 0.f, my = 0.f, cb = 0.f;
        for (int e = 0; e < 64; ++e) {
            float wv = Wp1[e * 512 + k];
            mx = fmaf(Wsp[e],      wv, mx);
            my = fmaf(Wsp[64 + e], wv, my);
            cb = fmaf(bsp[e],      wv, cb);
        }
        ((float*)(ws + MX_OFF))[k] = 0.05f * a1 * mx;
        ((float*)(ws + MY_OFF))[k] = 0.05f * a1 * my;
        ((float*)(ws + CB_OFF))[k] = 0.05f * a1 * cb + (bp1[k] - mp1[k]) * a1 + btp1[k];
        ((float*)(ws + SH_OFF))[k] = 0.05f * a1;
    } else if (t < 65536 + 512 + 1024) {
        int n = t - 66048;
        float a = gp2[n] * rsqrtf(vp2[n] + 1e-5f);
        ((float*)(ws + A2_OFF))[n] = a;
        ((float*)(ws + C2_OFF))[n] = btp2[n] + (bp2[n] - mp2[n]) * a;
    }
}

// ---------------------------------------------------------------------------
// prep_hh: HH[r][k] = 0.05*a1[k]*sum_q h[r][q]*Wp1[64+q][k] + CB[k], bf16.
// One block per 16 rows; Wp1 reads coalesced over k; 268 MFLOP total.
// ---------------------------------------------------------------------------
__global__ __launch_bounds__(256) void prep_hh_kernel(
    const float* __restrict__ hst, const float* __restrict__ Wp1,
    unsigned char* __restrict__ ws)
{
    __shared__ float hl[1024];              // 16 rows x 64
    int r0 = blockIdx.x * 16;
    int tid = threadIdx.x;
    ((float4*)hl)[tid] = ((const float4*)(hst + r0 * 64))[tid];
    __syncthreads();
    const float* SH = (const float*)(ws + SH_OFF);
    const float* CB = (const float*)(ws + CB_OFF);
    unsigned short* HH = (unsigned short*)(ws + HH_OFF);
    #pragma unroll
    for (int kk = 0; kk < 2; ++kk) {
        int k = tid + kk * 256;
        float sh = SH[k], cb = CB[k];
        float acc[16];
        #pragma unroll
        for (int j = 0; j < 16; ++j) acc[j] = 0.f;
        for (int q = 0; q < 64; ++q) {
            float wv = Wp1[(64 + q) * 512 + k];
            #pragma unroll
            for (int j = 0; j < 16; ++j) acc[j] = fmaf(hl[j * 64 + q], wv, acc[j]);
        }
        #pragma unroll
        for (int j = 0; j < 16; ++j)
            HH[(r0 + j) * 512 + k] = f2bf(fmaf(acc[j], sh, cb));
    }
}

// ---------------------------------------------------------------------------
// mm2: WG = (scene-pair sp, N-quarter nq). 256 thr = 4 waves, wave w owns
// ntiles nq*16+w*4 .. +4 (64 cols). Rows: 32 rowtiles (2 scenes x 16 i),
// processed in 4 R-blocks of 8 (scene-uniform per block). Per (ks, block):
// one HH frag (2x ds_read_b128, shared by all 8 rowtiles!) + MX/MY frags
// (broadcast) + 8 on-the-fly A-frag constructions + 4 B-frags + 32 MFMA.
// LDS: HH f32 [32][2048B] swizzled(^(row&7)<<5) | RELX/RELY | MX/MY | posf.
// ---------------------------------------------------------------------------
__global__ __launch_bounds__(256) __attribute__((amdgpu_waves_per_eu(2, 2)))
void mm2_kernel(const float* __restrict__ epos,
                const unsigned char* __restrict__ ws,
                float* __restrict__ out)
{
    __shared__ unsigned char smem[73984];
    float* RELX = (float*)(smem + 65536);
    float* RELY = (float*)(smem + 67584);
    float* MXl  = (float*)(smem + 69632);
    float* MYl  = (float*)(smem + 71680);
    float* posf = (float*)(smem + 73728);

    const int sp  = blockIdx.x >> 2;     // 128 scene pairs
    const int nq  = blockIdx.x & 3;      // 4 N-quarters
    const int tid = threadIdx.x;
    const int w   = tid >> 6;
    const int l   = tid & 63;
    const int quad = l >> 4;
    const int jl   = l & 15;

    if (tid < 64) posf[tid] = epos[sp * 64 + tid];
    {
        const float* mx = (const float*)(ws + MX_OFF);
        const float* my = (const float*)(ws + MY_OFF);
        MXl[tid] = mx[tid]; MXl[256 + tid] = mx[256 + tid];
        MYl[tid] = my[tid]; MYl[256 + tid] = my[256 + tid];
    }
    __syncthreads();
    // rel for 2 scenes (512 (i,j) pairs)
    #pragma unroll
    for (int it = 0; it < 2; ++it) {
        int e = tid + it * 256;
        int sc = e >> 8, i = (e >> 4) & 15, j = e & 15;
        RELX[e] = posf[sc * 32 + j * 2]     - posf[sc * 32 + i * 2];
        RELY[e] = posf[sc * 32 + j * 2 + 1] - posf[sc * 32 + i * 2 + 1];
    }
    // stage HH (32 rows x 512 k, bf16 -> f32, swizzled)
    {
        const uint4* src = (const uint4*)(ws + HH_OFF) + sp * 2048;
        #pragma unroll
        for (int it = 0; it < 8; ++it) {
            int c = tid + it * 256;          // 16B chunk = 8 bf16
            int row = c >> 6, p16 = c & 63;
            uint4 d = src[c];
            f32x4 f0, f1;
            f0[0] = bfbits2f(d.x << 16); f0[1] = bfbits2f(d.x & 0xffff0000u);
            f0[2] = bfbits2f(d.y << 16); f0[3] = bfbits2f(d.y & 0xffff0000u);
            f1[0] = bfbits2f(d.z << 16); f1[1] = bfbits2f(d.z & 0xffff0000u);
            f1[2] = bfbits2f(d.w << 16); f1[3] = bfbits2f(d.w & 0xffff0000u);
            int ba = row * 2048 + ((p16 * 32) ^ ((row & 7) << 5));
            *(f32x4*)(smem + ba)      = f0;
            *(f32x4*)(smem + ba + 16) = f1;
        }
    }
    __syncthreads();

    // hoist per-column epilogue constants
    float a2r[4], c2r[4];
    #pragma unroll
    for (int ct = 0; ct < 4; ++ct) {
        int col = (nq * 16 + w * 4 + ct) * 16 + jl;
        a2r[ct] = ((const float*)(ws + A2_OFF))[col];
        c2r[ct] = ((const float*)(ws + C2_OFF))[col];
    }

    const f32x4 fzero = {0.f, 0.f, 0.f, 0.f};
    const unsigned char* bws = ws + BP2_OFF;

    #pragma unroll 1
    for (int b = 0; b < 4; ++b) {
        const int sc = b >> 1;
        float rx[8], ry[8];
        #pragma unroll
        for (int r = 0; r < 8; ++r) {
            int i = (b & 1) * 8 + r;
            rx[r] = RELX[sc * 256 + i * 16 + jl];
            ry[r] = RELY[sc * 256 + i * 16 + jl];
        }
        f32x4 acc[8][4];
        #pragma unroll
        for (int r = 0; r < 8; ++r)
            #pragma unroll
            for (int ct = 0; ct < 4; ++ct) acc[r][ct] = fzero;

        #pragma unroll 4
        for (int ks = 0; ks < 16; ++ks) {
            // B-frags for this wave's 4 ntiles
            bf16x8 bfr[4];
            #pragma unroll
            for (int ct = 0; ct < 4; ++ct) {
                int nt = nq * 16 + w * 4 + ct;
                bfr[ct] = *(const bf16x8*)(bws + (((nt * 16 + ks) * 64 + l) << 4));
            }
            // MX/MY fragment (broadcast within quad), k = ks*32 + quad*8 + t
            int mb = ks * 32 + quad * 8;
            f32x4 mx0 = *(const f32x4*)(MXl + mb), mx1 = *(const f32x4*)(MXl + mb + 4);
            f32x4 my0 = *(const f32x4*)(MYl + mb), my1 = *(const f32x4*)(MYl + mb + 4);
            // HH fragment: row = sc*16 + jl -- shared by all 8 rowtiles
            int row = sc * 16 + jl;
            int ha = row * 2048 + ((ks * 128 + quad * 32) ^ ((jl & 7) << 5));
            f32x4 hh0 = *(const f32x4*)(smem + ha);
            f32x4 hh1 = *(const f32x4*)(smem + ha + 16);

            #pragma unroll
            for (int r = 0; r < 8; ++r) {
                float y0 = fmaxf(fmaf(rx[r], mx0[0], fmaf(ry[r], my0[0], hh0[0])), 0.f);
                float y1 = fmaxf(fmaf(rx[r], mx0[1], fmaf(ry[r], my0[1], hh0[1])), 0.f);
                float y2 = fmaxf(fmaf(rx[r], mx0[2], fmaf(ry[r], my0[2], hh0[2])), 0.f);
                float y3 = fmaxf(fmaf(rx[r], mx0[3], fmaf(ry[r], my0[3], hh0[3])), 0.f);
                float y4 = fmaxf(fmaf(rx[r], mx1[0], fmaf(ry[r], my1[0], hh1[0])), 0.f);
                float y5 = fmaxf(fmaf(rx[r], mx1[1], fmaf(ry[r], my1[1], hh1[1])), 0.f);
                float y6 = fmaxf(fmaf(rx[r], mx1[2], fmaf(ry[r], my1[2], hh1[2])), 0.f);
                float y7 = fmaxf(fmaf(rx[r], mx1[3], fmaf(ry[r], my1[3], hh1[3])), 0.f);
                union { bf16x8 v; unsigned u[4]; } af;
                af.u[0] = pk_bf16(y0, y1);
                af.u[1] = pk_bf16(y2, y3);
                af.u[2] = pk_bf16(y4, y5);
                af.u[3] = pk_bf16(y6, y7);
                #pragma unroll
                for (int ct = 0; ct < 4; ++ct)
                    acc[r][ct] = __builtin_amdgcn_mfma_f32_16x16x32_bf16(af.v, bfr[ct], acc[r][ct], 0, 0, 0);
            }
        }
        // epilogue: bn+relu, max over j (D rows = j), store fp32
        #pragma unroll
        for (int ct = 0; ct < 4; ++ct) {
            #pragma unroll
            for (int r = 0; r < 8; ++r) {
                float v0 = fmaxf(fmaf(acc[r][ct][0], a2r[ct], c2r[ct]), 0.f);
                float v1 = fmaxf(fmaf(acc[r][ct][1], a2r[ct], c2r[ct]), 0.f);
                float v2 = fmaxf(fmaf(acc[r][ct][2], a2r[ct], c2r[ct]), 0.f);
                float v3 = fmaxf(fmaf(acc[r][ct][3], a2r[ct], c2r[ct]), 0.f);
                float v = fmaxf(fmaxf(v0, v1), fmaxf(v2, v3));
                v = fmaxf(v, __shfl_xor(v, 16, 64));
                v = fmaxf(v, __shfl_xor(v, 32, 64));
                if (l < 16) {
                    int i = (b & 1) * 8 + r;
                    int orow = (sp * 2 + sc) * 16 + i;
                    int col = (nq * 16 + w * 4 + ct) * 16 + l;
                    __builtin_nontemporal_store(v, &out[orow * 1024 + col]);
                }
            }
        }
    }
}

extern "C" void kernel_launch(void* const* d_in, const int* in_sizes, int n_in,
                              void* d_out, int out_size, void* d_ws, size_t ws_size,
                              hipStream_t stream) {
    const float* hst  = (const float*)d_in[0];
    const float* epos = (const float*)d_in[1];
    const float* Wsp  = (const float*)d_in[4];
    const float* bsp  = (const float*)d_in[5];
    const float* Wp1  = (const float*)d_in[20];
    const float* bp1  = (const float*)d_in[21];
    const float* gp1  = (const float*)d_in[22];
    const float* btp1 = (const float*)d_in[23];
    const float* mp1  = (const float*)d_in[24];
    const float* vp1  = (const float*)d_in[25];
    const float* Wp2  = (const float*)d_in[26];
    const float* bp2  = (const float*)d_in[27];
    const float* gp2  = (const float*)d_in[28];
    const float* btp2 = (const float*)d_in[29];
    const float* mp2  = (const float*)d_in[30];
    const float* vp2  = (const float*)d_in[31];
    unsigned char* ws = (unsigned char*)d_ws;
    float* out = (float*)d_out;

    // 65536 (pack2) + 512 (consts) + 1024 (A2/C2) = 67072 threads
    prep1_kernel<<<262, 256, 0, stream>>>(Wsp, bsp, Wp1, bp1, gp1, btp1, mp1, vp1,
                                          Wp2, bp2, gp2, btp2, mp2, vp2, ws);
    prep_hh_kernel<<<256, 256, 0, stream>>>(hst, Wp1, ws);
    // 128 scene-pairs x 4 N-quarters
    mm2_kernel<<<512, 256, 0, stream>>>(epos, ws, out);
}

// Round 5
// 248.916 us; speedup vs baseline: 1.9571x; 1.1734x over previous
//
#include <hip/hip_runtime.h>
#include <hip/hip_bf16.h>
#include <stdint.h>

// ---------------------------------------------------------------------------
// E=64 H=64 PRE1=512 BNK=1024 S=256 P=16 B=4096. Attention branch dead
// (softmax over size-1 axis == 1). Decomposition (rel is rank-2):
//   Z1[s,i,j,k] = rx*MX[k] + ry*MY[k] + HH[16s+j][k];  Y1 = relu(Z1)
//   out = maxpool_j relu(bn2(Y1 @ Wp2))
// v4: spill-proof tiling. WG = (scene, N-16th), 4 waves x acc[4][4] (64 regs),
//     waves split i-rowtiles (disjoint -> no redundant A construction),
//     single K pass (no b-loop), float2 packed construction (v_pk_fma_f32).
//     LDS 38 KB (HH f32 swizzled + rel + MX/MY).
// ---------------------------------------------------------------------------

typedef __bf16 bf16x8 __attribute__((ext_vector_type(8)));
typedef __bf16 bf16x2 __attribute__((ext_vector_type(2)));
typedef float  f32x4  __attribute__((ext_vector_type(4)));
typedef float  f32x2  __attribute__((ext_vector_type(2)));

// workspace layout (bytes)
#define BP2_OFF 0                         // packed Wp2 bf16: 64nt*16kb*64l*16B = 1 MB
#define HH_OFF  (1u<<20)                  // HH bf16 [4096][512] = 4 MB
#define MX_OFF  (HH_OFF + (4u<<20))       // 512 f32
#define MY_OFF  (MX_OFF + 2048)           // 512 f32
#define CB_OFF  (MY_OFF + 2048)           // 512 f32
#define SH_OFF  (CB_OFF + 2048)           // 512 f32 (0.05*a1)
#define A2_OFF  (SH_OFF + 2048)           // 1024 f32
#define C2_OFF  (A2_OFF + 4096)           // 1024 f32

// LDS layout (bytes)
#define HH_LDS 0        // f32 [16][512], row stride 2048, swizzle ^((row&7)<<5)
#define RX_LDS 32768    // f32 [256]
#define RY_LDS 33792    // f32 [256]
#define MX_LDS 34816    // f32 [512]
#define MY_LDS 36864    // f32 [512]
#define PF_LDS 38912    // f32 [32]
#define LDS_SZ 39040

__device__ __forceinline__ unsigned short f2bf(float f) {
    union { float f; unsigned u; } c; c.f = f;
    unsigned u = c.u;
    return (unsigned short)((u + 0x7fffu + ((u >> 16) & 1u)) >> 16);
}
__device__ __forceinline__ float bfbits2f(unsigned hi) {
    union { unsigned u; float f; } c; c.u = hi; return c.f;
}
__device__ __forceinline__ unsigned pk_bf16(float a, float b) {
#if __has_builtin(__builtin_amdgcn_cvt_pk_bf16_f32)
    bf16x2 p = __builtin_amdgcn_cvt_pk_bf16_f32(a, b);
    union { bf16x2 v; unsigned u; } c; c.v = p; return c.u;
#else
    return (unsigned)f2bf(a) | ((unsigned)f2bf(b) << 16);
#endif
}

// ---------------------------------------------------------------------------
// prep1: pack Wp2 into MFMA B-frag order + fold all BN/bias/0.05 constants.
// B-frag (16x16x32): lane l holds B[k=kb*32+(l>>4)*8+j][n=nt*16+(l&15)],
// packed at ((nt*16+kb)*64+l)*16 bytes.
// ---------------------------------------------------------------------------
__global__ void prep1_kernel(
    const float* __restrict__ Wsp,  const float* __restrict__ bsp,
    const float* __restrict__ Wp1,  const float* __restrict__ bp1,
    const float* __restrict__ gp1,  const float* __restrict__ btp1,
    const float* __restrict__ mp1,  const float* __restrict__ vp1,
    const float* __restrict__ Wp2,  const float* __restrict__ bp2,
    const float* __restrict__ gp2,  const float* __restrict__ btp2,
    const float* __restrict__ mp2,  const float* __restrict__ vp2,
    unsigned char* __restrict__ ws)
{
    int t = blockIdx.x * 256 + threadIdx.x;
    if (t < 65536) {
        int nt = t >> 10, kb = (t >> 6) & 15, l = t & 63;
        int n  = nt * 16 + (l & 15);
        int k0 = kb * 32 + (l >> 4) * 8;
        unsigned w0, w1, w2, w3;
        w0 = f2bf(Wp2[(k0+0)*1024+n]) | ((unsigned)f2bf(Wp2[(k0+1)*1024+n]) << 16);
        w1 = f2bf(Wp2[(k0+2)*1024+n]) | ((unsigned)f2bf(Wp2[(k0+3)*1024+n]) << 16);
        w2 = f2bf(Wp2[(k0+4)*1024+n]) | ((unsigned)f2bf(Wp2[(k0+5)*1024+n]) << 16);
        w3 = f2bf(Wp2[(k0+6)*1024+n]) | ((unsigned)f2bf(Wp2[(k0+7)*1024+n]) << 16);
        uint4 v; v.x = w0; v.y = w1; v.z = w2; v.w = w3;
        ((uint4*)(ws + BP2_OFF))[t] = v;
    } else if (t < 65536 + 512) {
        int k = t - 65536;
        float a1 = gp1[k] * rsqrtf(vp1[k] + 1e-5f);
        float mx = 0.f, my = 0.f, cb = 0.f;
        for (int e = 0; e < 64; ++e) {
            float wv = Wp1[e * 512 + k];
            mx = fmaf(Wsp[e],      wv, mx);
            my = fmaf(Wsp[64 + e], wv, my);
            cb = fmaf(bsp[e],      wv, cb);
        }
        ((float*)(ws + MX_OFF))[k] = 0.05f * a1 * mx;
        ((float*)(ws + MY_OFF))[k] = 0.05f * a1 * my;
        ((float*)(ws + CB_OFF))[k] = 0.05f * a1 * cb + (bp1[k] - mp1[k]) * a1 + btp1[k];
        ((float*)(ws + SH_OFF))[k] = 0.05f * a1;
    } else if (t < 65536 + 512 + 1024) {
        int n = t - 66048;
        float a = gp2[n] * rsqrtf(vp2[n] + 1e-5f);
        ((float*)(ws + A2_OFF))[n] = a;
        ((float*)(ws + C2_OFF))[n] = btp2[n] + (bp2[n] - mp2[n]) * a;
    }
}

// ---------------------------------------------------------------------------
// prep_hh: HH[r][k] = 0.05*a1[k]*sum_q h[r][q]*Wp1[64+q][k] + CB[k], bf16.
// ---------------------------------------------------------------------------
__global__ __launch_bounds__(256) void prep_hh_kernel(
    const float* __restrict__ hst, const float* __restrict__ Wp1,
    unsigned char* __restrict__ ws)
{
    __shared__ float hl[1024];              // 16 rows x 64
    int r0 = blockIdx.x * 16;
    int tid = threadIdx.x;
    ((float4*)hl)[tid] = ((const float4*)(hst + r0 * 64))[tid];
    __syncthreads();
    const float* SH = (const float*)(ws + SH_OFF);
    const float* CB = (const float*)(ws + CB_OFF);
    unsigned short* HH = (unsigned short*)(ws + HH_OFF);
    #pragma unroll
    for (int kk = 0; kk < 2; ++kk) {
        int k = tid + kk * 256;
        float sh = SH[k], cb = CB[k];
        float acc[16];
        #pragma unroll
        for (int j = 0; j < 16; ++j) acc[j] = 0.f;
        for (int q = 0; q < 64; ++q) {
            float wv = Wp1[(64 + q) * 512 + k];
            #pragma unroll
            for (int j = 0; j < 16; ++j) acc[j] = fmaf(hl[j * 64 + q], wv, acc[j]);
        }
        #pragma unroll
        for (int j = 0; j < 16; ++j)
            HH[(r0 + j) * 512 + k] = f2bf(fmaf(acc[j], sh, cb));
    }
}

// ---------------------------------------------------------------------------
// mm2 v4: WG = (scene s, N-16th ntq). 256 thr = 4 waves.
// Wave w: rowtiles i = w*4..w*4+3 (disjoint), ntiles nt = ntq*4..+3 (shared,
// L1-broadcast). acc[4][4] = 64 VGPRs, single K pass (16 ks).
// A-frag built on the fly: lane (jl,quad) holds y[j=jl][k=ks*32+quad*8+t],
// y = relu(rx(i,j)*MX[k] + ry(i,j)*MY[k] + HH[16s+j][k]) via packed f32 math.
// C/D layout: lane holds D[row=quad*4+reg][col=jl]; D-rows = j -> maxpool is
// 4-reg max + 2 shfl_xor.
// ---------------------------------------------------------------------------
__global__ __launch_bounds__(256, 2) void mm2_kernel(
    const float* __restrict__ epos,
    const unsigned char* __restrict__ ws,
    float* __restrict__ out)
{
    __shared__ unsigned char smem[LDS_SZ];
    float* RELX = (float*)(smem + RX_LDS);
    float* RELY = (float*)(smem + RY_LDS);
    float* posf = (float*)(smem + PF_LDS);

    const int s   = blockIdx.x >> 4;     // 256 scenes
    const int ntq = blockIdx.x & 15;     // 16 N-16ths (4 ntiles each)
    const int tid = threadIdx.x;
    const int w    = tid >> 6;
    const int l    = tid & 63;
    const int quad = l >> 4;
    const int jl   = l & 15;

    // ---- stage posf, MX/MY, HH (independent) ----
    if (tid < 32) posf[tid] = epos[s * 32 + tid];
    {
        const float* mx = (const float*)(ws + MX_OFF);
        const float* my = (const float*)(ws + MY_OFF);
        ((float*)(smem + MX_LDS))[tid]       = mx[tid];
        ((float*)(smem + MX_LDS))[tid + 256] = mx[tid + 256];
        ((float*)(smem + MY_LDS))[tid]       = my[tid];
        ((float*)(smem + MY_LDS))[tid + 256] = my[tid + 256];
    }
    {
        // HH rows 16s..16s+15: 16 x 512 bf16 = 1024 uint4, -> f32 swizzled
        const uint4* src = (const uint4*)(ws + HH_OFF) + s * 1024;
        #pragma unroll
        for (int it = 0; it < 4; ++it) {
            int c = tid + it * 256;
            int row = c >> 6, p16 = c & 63;     // p16: which 8-bf16 chunk
            uint4 d = src[c];
            f32x4 f0, f1;
            f0[0] = bfbits2f(d.x << 16); f0[1] = bfbits2f(d.x & 0xffff0000u);
            f0[2] = bfbits2f(d.y << 16); f0[3] = bfbits2f(d.y & 0xffff0000u);
            f1[0] = bfbits2f(d.z << 16); f1[1] = bfbits2f(d.z & 0xffff0000u);
            f1[2] = bfbits2f(d.w << 16); f1[3] = bfbits2f(d.w & 0xffff0000u);
            int ba = row * 2048 + ((p16 * 32) ^ ((row & 7) << 5));
            *(f32x4*)(smem + HH_LDS + ba)      = f0;
            *(f32x4*)(smem + HH_LDS + ba + 16) = f1;
        }
    }
    __syncthreads();
    // rel for this scene (256 (i,j) pairs)
    {
        int i = tid >> 4, j = tid & 15;
        RELX[tid] = posf[j * 2]     - posf[i * 2];
        RELY[tid] = posf[j * 2 + 1] - posf[i * 2 + 1];
    }
    __syncthreads();

    // per-lane rx/ry for this wave's 4 rowtiles (i = w*4+rb, j = jl)
    float rxv[4], ryv[4];
    #pragma unroll
    for (int rb = 0; rb < 4; ++rb) {
        rxv[rb] = RELX[(w * 4 + rb) * 16 + jl];
        ryv[rb] = RELY[(w * 4 + rb) * 16 + jl];
    }

    const f32x4 fzero = {0.f, 0.f, 0.f, 0.f};
    f32x4 acc[4][4];
    #pragma unroll
    for (int rb = 0; rb < 4; ++rb)
        #pragma unroll
        for (int ct = 0; ct < 4; ++ct) acc[rb][ct] = fzero;

    const unsigned char* bws = ws + BP2_OFF;
    const f32x2 zero2 = {0.f, 0.f};

    #pragma unroll 1
    for (int ks = 0; ks < 16; ++ks) {
        // B-frags (4 ntiles, identical addrs across the 4 waves -> L1)
        bf16x8 bfr[4];
        #pragma unroll
        for (int ct = 0; ct < 4; ++ct) {
            int nt = ntq * 4 + ct;
            bfr[ct] = *(const bf16x8*)(bws + (((nt * 16 + ks) * 64 + l) << 4));
        }
        // MX/MY/HH for k = ks*32 + quad*8 .. +8
        int mo = (ks * 32 + quad * 8) * 4;
        f32x4 mx0 = *(const f32x4*)(smem + MX_LDS + mo);
        f32x4 mx1 = *(const f32x4*)(smem + MX_LDS + mo + 16);
        f32x4 my0 = *(const f32x4*)(smem + MY_LDS + mo);
        f32x4 my1 = *(const f32x4*)(smem + MY_LDS + mo + 16);
        int ha = jl * 2048 + ((ks * 128 + quad * 32) ^ ((jl & 7) << 5));
        f32x4 hh0 = *(const f32x4*)(smem + HH_LDS + ha);
        f32x4 hh1 = *(const f32x4*)(smem + HH_LDS + ha + 16);

        f32x2 mxp[4] = { __builtin_shufflevector(mx0, mx0, 0, 1),
                         __builtin_shufflevector(mx0, mx0, 2, 3),
                         __builtin_shufflevector(mx1, mx1, 0, 1),
                         __builtin_shufflevector(mx1, mx1, 2, 3) };
        f32x2 myp[4] = { __builtin_shufflevector(my0, my0, 0, 1),
                         __builtin_shufflevector(my0, my0, 2, 3),
                         __builtin_shufflevector(my1, my1, 0, 1),
                         __builtin_shufflevector(my1, my1, 2, 3) };
        f32x2 hhp[4] = { __builtin_shufflevector(hh0, hh0, 0, 1),
                         __builtin_shufflevector(hh0, hh0, 2, 3),
                         __builtin_shufflevector(hh1, hh1, 0, 1),
                         __builtin_shufflevector(hh1, hh1, 2, 3) };

        #pragma unroll
        for (int rb = 0; rb < 4; ++rb) {
            f32x2 rx2 = { rxv[rb], rxv[rb] };
            f32x2 ry2 = { ryv[rb], ryv[rb] };
            union { unsigned u[4]; bf16x8 v; } af;
            #pragma unroll
            for (int p = 0; p < 4; ++p) {
                f32x2 t = __builtin_elementwise_fma(ry2, myp[p], hhp[p]);
                t = __builtin_elementwise_fma(rx2, mxp[p], t);
                t = __builtin_elementwise_max(t, zero2);
                af.u[p] = pk_bf16(t[0], t[1]);
            }
            #pragma unroll
            for (int ct = 0; ct < 4; ++ct)
                acc[rb][ct] = __builtin_amdgcn_mfma_f32_16x16x32_bf16(af.v, bfr[ct], acc[rb][ct], 0, 0, 0);
        }
    }

    // ---- epilogue: bn2 + relu, maxpool over j, store fp32 ----
    const float* A2 = (const float*)(ws + A2_OFF);
    const float* C2 = (const float*)(ws + C2_OFF);
    #pragma unroll
    for (int ct = 0; ct < 4; ++ct) {
        int col = (ntq * 4 + ct) * 16 + jl;
        float a2 = A2[col], c2 = C2[col];
        #pragma unroll
        for (int rb = 0; rb < 4; ++rb) {
            float v0 = fmaxf(fmaf(acc[rb][ct][0], a2, c2), 0.f);
            float v1 = fmaxf(fmaf(acc[rb][ct][1], a2, c2), 0.f);
            float v2 = fmaxf(fmaf(acc[rb][ct][2], a2, c2), 0.f);
            float v3 = fmaxf(fmaf(acc[rb][ct][3], a2, c2), 0.f);
            float v = fmaxf(fmaxf(v0, v1), fmaxf(v2, v3));
            v = fmaxf(v, __shfl_xor(v, 16, 64));
            v = fmaxf(v, __shfl_xor(v, 32, 64));
            if (l < 16) {
                int orow = s * 16 + w * 4 + rb;
                __builtin_nontemporal_store(v, &out[orow * 1024 + col]);
            }
        }
    }
}

extern "C" void kernel_launch(void* const* d_in, const int* in_sizes, int n_in,
                              void* d_out, int out_size, void* d_ws, size_t ws_size,
                              hipStream_t stream) {
    const float* hst  = (const float*)d_in[0];
    const float* epos = (const float*)d_in[1];
    const float* Wsp  = (const float*)d_in[4];
    const float* bsp  = (const float*)d_in[5];
    const float* Wp1  = (const float*)d_in[20];
    const float* bp1  = (const float*)d_in[21];
    const float* gp1  = (const float*)d_in[22];
    const float* btp1 = (const float*)d_in[23];
    const float* mp1  = (const float*)d_in[24];
    const float* vp1  = (const float*)d_in[25];
    const float* Wp2  = (const float*)d_in[26];
    const float* bp2  = (const float*)d_in[27];
    const float* gp2  = (const float*)d_in[28];
    const float* btp2 = (const float*)d_in[29];
    const float* mp2  = (const float*)d_in[30];
    const float* vp2  = (const float*)d_in[31];
    unsigned char* ws = (unsigned char*)d_ws;
    float* out = (float*)d_out;

    prep1_kernel<<<262, 256, 0, stream>>>(Wsp, bsp, Wp1, bp1, gp1, btp1, mp1, vp1,
                                          Wp2, bp2, gp2, btp2, mp2, vp2, ws);
    prep_hh_kernel<<<256, 256, 0, stream>>>(hst, Wp1, ws);
    // 256 scenes x 16 N-16ths
    mm2_kernel<<<4096, 256, 0, stream>>>(epos, ws, out);
}